// Round 1
// baseline (503.711 us; speedup 1.0000x reference)
//
#include <hip/hip_runtime.h>
#include <cstddef>

typedef short short8 __attribute__((ext_vector_type(8)));
typedef float f32x4 __attribute__((ext_vector_type(4)));

#define SS 1024
#define NH 16
#define DH 64
#define NB 4

static __device__ __forceinline__ unsigned short f2bf(float f) {
    union { float f; unsigned int i; } x; x.f = f;
    unsigned int r = x.i + 0x7FFFu + ((x.i >> 16) & 1u);
    return (unsigned short)(r >> 16);
}
static __device__ __forceinline__ float bf2f(unsigned short u) {
    union { unsigned int i; float f; } x; x.i = ((unsigned int)u) << 16;
    return x.f;
}

// ---------------- cast m_feats (4096x1024 fp32) -> bf16 ----------------
__global__ __launch_bounds__(256) void cast_mf(const float* __restrict__ in,
                                               unsigned short* __restrict__ out) {
    size_t i = ((size_t)blockIdx.x * 256 + threadIdx.x) * 4;
    float4 v = *(const float4*)(in + i);
    short4 o;
    o.x = (short)f2bf(v.x); o.y = (short)f2bf(v.y);
    o.z = (short)f2bf(v.z); o.w = (short)f2bf(v.w);
    *(short4*)(out + i) = o;
}

// ------- transpose-cast W_v (1024x1024) ++ W_c (1024x2048) -> WT bf16 [3072][1024] -------
// WT row n: n<1024 -> W_v col n ; 1024<=n<3072 -> W_c col n-1024
__global__ __launch_bounds__(256) void transpose_w(const float* __restrict__ Wv,
                                                   const float* __restrict__ Wc,
                                                   unsigned short* __restrict__ WT) {
    __shared__ float tile[32][33];
    int n0 = blockIdx.x * 32, k0 = blockIdx.y * 32;
    int t = threadIdx.x;
    int kr = t >> 3, nc = (t & 7) * 4;
    const float* src; int ld; int nn = n0 + nc;
    if (n0 < 1024) { src = Wv; ld = 1024; } else { src = Wc; ld = 2048; nn -= 1024; }
    float4 v = *(const float4*)(src + (size_t)(k0 + kr) * ld + nn);
    tile[kr][nc + 0] = v.x; tile[kr][nc + 1] = v.y;
    tile[kr][nc + 2] = v.z; tile[kr][nc + 3] = v.w;
    __syncthreads();
    int nr = t >> 3, kc = (t & 7) * 4;
    short4 o;
    o.x = (short)f2bf(tile[kc + 0][nr]); o.y = (short)f2bf(tile[kc + 1][nr]);
    o.z = (short)f2bf(tile[kc + 2][nr]); o.w = (short)f2bf(tile[kc + 3][nr]);
    *(short4*)(WT + (size_t)(n0 + nr) * 1024 + k0 + kc) = o;
}

// ---------------- GEMM: C[4096][3072] = A[4096][1024] * B ; BT form ----------------
// cols 0..1023 -> m_k, 1024..2047 -> m_q  (kq buffer, [4096][2048] bf16)
// cols 2048..3071 -> m_v, written TRANSPOSED into mvT[b][h][d][j] bf16
__global__ __launch_bounds__(256) void gemm_kqv(const unsigned short* __restrict__ A,
                                                const unsigned short* __restrict__ BT,
                                                const float* __restrict__ bv,
                                                const float* __restrict__ bc,
                                                unsigned short* __restrict__ kq,
                                                unsigned short* __restrict__ mvT) {
    __shared__ __align__(16) unsigned short As[128 * 40];
    __shared__ __align__(16) unsigned short Bs[128 * 40];
    int m0 = blockIdx.y * 128;
    int n0 = blockIdx.x * 128;
    int tid = threadIdx.x, lane = tid & 63, wv = tid >> 6;
    int wm = wv >> 1, wn = wv & 1;
    int lq = lane & 15, quad = lane >> 4;

    f32x4 zero = {0.f, 0.f, 0.f, 0.f};
    f32x4 acc[4][4];
#pragma unroll
    for (int i = 0; i < 4; ++i)
#pragma unroll
        for (int j = 0; j < 4; ++j) acc[i][j] = zero;

    int srow = tid >> 2, sch = tid & 3;  // staging: row 0..63 (+64), chunk of 8 elems

    for (int kt = 0; kt < 1024; kt += 32) {
        __syncthreads();
        int4 va0 = *(const int4*)(A + (size_t)(m0 + srow) * 1024 + kt + sch * 8);
        int4 va1 = *(const int4*)(A + (size_t)(m0 + srow + 64) * 1024 + kt + sch * 8);
        int4 vb0 = *(const int4*)(BT + (size_t)(n0 + srow) * 1024 + kt + sch * 8);
        int4 vb1 = *(const int4*)(BT + (size_t)(n0 + srow + 64) * 1024 + kt + sch * 8);
        *(int4*)(As + srow * 40 + sch * 8) = va0;
        *(int4*)(As + (srow + 64) * 40 + sch * 8) = va1;
        *(int4*)(Bs + srow * 40 + sch * 8) = vb0;
        *(int4*)(Bs + (srow + 64) * 40 + sch * 8) = vb1;
        __syncthreads();

        short8 af[4], bf[4];
#pragma unroll
        for (int i = 0; i < 4; ++i) {
            af[i] = *(const short8*)(As + (wm * 64 + i * 16 + lq) * 40 + quad * 8);
            bf[i] = *(const short8*)(Bs + (wn * 64 + i * 16 + lq) * 40 + quad * 8);
        }
#pragma unroll
        for (int mi = 0; mi < 4; ++mi)
#pragma unroll
            for (int ni = 0; ni < 4; ++ni)
                acc[mi][ni] = __builtin_amdgcn_mfma_f32_16x16x32_bf16(af[mi], bf[ni], acc[mi][ni], 0, 0, 0);
    }

    // epilogue: bias + store (C layout: row = quad*4+reg, col = lq)
#pragma unroll
    for (int mi = 0; mi < 4; ++mi) {
#pragma unroll
        for (int ni = 0; ni < 4; ++ni) {
            int colg = n0 + wn * 64 + ni * 16 + lq;
            float bias = (colg < 1024) ? bv[colg] : bc[colg - 1024];
            if (colg < 2048) {
#pragma unroll
                for (int r = 0; r < 4; ++r) {
                    int rowg = m0 + wm * 64 + mi * 16 + quad * 4 + r;
                    kq[(size_t)rowg * 2048 + colg] = f2bf(acc[mi][ni][r] + bias);
                }
            } else {
                int c = colg - 2048; int hh = c >> 6, d = c & 63;
#pragma unroll
                for (int r = 0; r < 4; ++r) {
                    int rowg = m0 + wm * 64 + mi * 16 + quad * 4 + r;
                    int bb = rowg >> 10, j = rowg & 1023;
                    mvT[(((size_t)bb * NH + hh) * DH + d) * 1024 + j] = f2bf(acc[mi][ni][r] + bias);
                }
            }
        }
    }
}

// ---------------- fused attention ----------------
// block = (b, h, 16-row i-tile). scores[i][j] = sum_d mk[i][d]*mq[j][d] / 8
// mask over j, softmax over j; w written; r = sum_j w*mv accumulated unnormalized.
__global__ __launch_bounds__(256) void attn_kernel(const unsigned short* __restrict__ kq,
                                                   const unsigned short* __restrict__ mvT,
                                                   const int* __restrict__ mask,
                                                   const float* __restrict__ m_feats,
                                                   float* __restrict__ out0,
                                                   float* __restrict__ out1) {
    __shared__ __align__(16) unsigned short mk_s[16 * 72];
    __shared__ __align__(16) unsigned short s_exp[16 * 1032];
    __shared__ float wsum[4][16];
    __shared__ float inv_s[16];

    int tid = threadIdx.x;
    int lane = tid & 63, wv = tid >> 6;
    int lq = lane & 15, quad = lane >> 4;

    int blk = blockIdx.x;
    int it = blk & 63;
    int bh = blk >> 6;
    int h = bh & (NH - 1), b = bh >> 4;
    int i0 = it * 16;

    // stage mk tile (16 rows x 64 d), padded stride 72
    if (tid < 128) {
        int row = tid >> 3, ch = tid & 7;
        int4 v = *(const int4*)(kq + (size_t)(b * SS + i0 + row) * 2048 + h * 64 + ch * 8);
        *(int4*)(mk_s + row * 72 + ch * 8) = v;
    }
    __syncthreads();

    short8 a0 = *(const short8*)(mk_s + lq * 72 + 0 * 32 + quad * 8);
    short8 a1 = *(const short8*)(mk_s + lq * 72 + 1 * 32 + quad * 8);

    float sums[4] = {0.f, 0.f, 0.f, 0.f};
    const float SC = 0.18033688011112042f;  // log2(e)/8
    const unsigned short* mqbase = kq + 1024 + h * 64 + quad * 8;

    for (int jt = wv * 16; jt < SS; jt += 64) {
        int jg = jt + lq;
        size_t rowoff = (size_t)(b * SS + jg) * 2048;
        short8 b0 = *(const short8*)(mqbase + rowoff);
        short8 b1 = *(const short8*)(mqbase + rowoff + 32);
        int mval = mask[b * SS + jg];
        f32x4 acc = {0.f, 0.f, 0.f, 0.f};
        acc = __builtin_amdgcn_mfma_f32_16x16x32_bf16(a0, b0, acc, 0, 0, 0);
        acc = __builtin_amdgcn_mfma_f32_16x16x32_bf16(a1, b1, acc, 0, 0, 0);
#pragma unroll
        for (int r = 0; r < 4; ++r) {
            float e = mval ? exp2f(acc[r] * SC) : 0.f;
            sums[r] += e;
            s_exp[(quad * 4 + r) * 1032 + jg] = f2bf(e);
        }
    }

    // row sums: reduce across the 16 lanes of each quad, then across waves
#pragma unroll
    for (int r = 0; r < 4; ++r) {
        float s = sums[r];
        s += __shfl_xor(s, 1); s += __shfl_xor(s, 2);
        s += __shfl_xor(s, 4); s += __shfl_xor(s, 8);
        if (lq == 0) wsum[wv][quad * 4 + r] = s;
    }
    __syncthreads();
    if (tid < 16) {
        float s = wsum[0][tid] + wsum[1][tid] + wsum[2][tid] + wsum[3][tid];
        inv_s[tid] = 1.0f / s;
    }
    __syncthreads();

    // PV: r[i][d] (wave wv owns d in [wv*16, wv*16+16)), K over all j
    f32x4 racc = {0.f, 0.f, 0.f, 0.f};
    const unsigned short* mvbase = mvT + ((size_t)bh * DH + wv * 16 + lq) * 1024 + quad * 8;
#pragma unroll 4
    for (int kt = 0; kt < 32; ++kt) {
        short8 bvf = *(const short8*)(mvbase + kt * 32);
        short8 ae = *(const short8*)(s_exp + lq * 1032 + kt * 32 + quad * 8);
        racc = __builtin_amdgcn_mfma_f32_16x16x32_bf16(ae, bvf, racc, 0, 0, 0);
    }

    // updated_m = m_feats + r * inv
#pragma unroll
    for (int r = 0; r < 4; ++r) {
        int row = quad * 4 + r;
        size_t o = (size_t)(b * SS + i0 + row) * 1024 + h * 64 + wv * 16 + lq;
        out0[o] = m_feats[o] + racc[r] * inv_s[row];
    }

    // write w (normalized), coalesced float4
    size_t wbase = ((size_t)bh * SS + i0) * SS;
    for (int idx = tid; idx < 4096; idx += 256) {
        int row = idx >> 8;
        int j = (idx & 255) * 4;
        float iv = inv_s[row];
        short4 ev = *(const short4*)(s_exp + row * 1032 + j);
        float4 wo;
        wo.x = bf2f((unsigned short)ev.x) * iv;
        wo.y = bf2f((unsigned short)ev.y) * iv;
        wo.z = bf2f((unsigned short)ev.z) * iv;
        wo.w = bf2f((unsigned short)ev.w) * iv;
        *(float4*)(out1 + wbase + (size_t)row * SS + j) = wo;
    }
}

extern "C" void kernel_launch(void* const* d_in, const int* in_sizes, int n_in,
                              void* d_out, int out_size, void* d_ws, size_t ws_size,
                              hipStream_t stream) {
    const float* m_feats = (const float*)d_in[0];
    const int*   mask    = (const int*)d_in[1];
    const float* W_c     = (const float*)d_in[2];
    const float* b_c     = (const float*)d_in[3];
    const float* W_v     = (const float*)d_in[4];
    const float* b_v     = (const float*)d_in[5];

    float* out0 = (float*)d_out;                       // updated_m: 4*1024*1024
    float* out1 = out0 + (size_t)NB * SS * 1024;       // w: 4*16*1024*1024

    unsigned short* mf_bf = (unsigned short*)d_ws;                 // 4096*1024
    unsigned short* WT    = mf_bf + (size_t)4096 * 1024;           // 3072*1024
    unsigned short* kq    = WT + (size_t)3072 * 1024;              // 4096*2048
    unsigned short* mvT   = kq + (size_t)4096 * 2048;              // 4*16*64*1024

    cast_mf<<<dim3(4096), dim3(256), 0, stream>>>(m_feats, mf_bf);
    transpose_w<<<dim3(96, 32), dim3(256), 0, stream>>>(W_v, W_c, WT);
    gemm_kqv<<<dim3(24, 32), dim3(256), 0, stream>>>(mf_bf, WT, b_v, b_c, kq, mvT);
    attn_kernel<<<dim3(4096), dim3(256), 0, stream>>>(kq, mvT, mask, m_feats, out0, out1);
}

// Round 3
// 496.009 us; speedup vs baseline: 1.0155x; 1.0155x over previous
//
#include <hip/hip_runtime.h>
#include <cstddef>

typedef short short8 __attribute__((ext_vector_type(8)));
typedef float f32x4 __attribute__((ext_vector_type(4)));

#define SS 1024
#define NH 16
#define DH 64
#define NB 4

static __device__ __forceinline__ unsigned short f2bf(float f) {
    union { float f; unsigned int i; } x; x.f = f;
    unsigned int r = x.i + 0x7FFFu + ((x.i >> 16) & 1u);
    return (unsigned short)(r >> 16);
}
static __device__ __forceinline__ float bf2f(unsigned short u) {
    union { unsigned int i; float f; } x; x.i = ((unsigned int)u) << 16;
    return x.f;
}

// async global->LDS 16B copy. Per-wave: lane l's lds ptr must be base + l*16.
static __device__ __forceinline__ void g2l16(const void* g, void* l) {
    __builtin_amdgcn_global_load_lds(
        (const __attribute__((address_space(1))) unsigned int*)g,
        (__attribute__((address_space(3))) unsigned int*)l, 16, 0, 0);
}

// ---------------- cast m_feats (4096x1024 fp32) -> bf16 ----------------
__global__ __launch_bounds__(256) void cast_mf(const float* __restrict__ in,
                                               unsigned short* __restrict__ out) {
    size_t i = ((size_t)blockIdx.x * 256 + threadIdx.x) * 4;
    float4 v = *(const float4*)(in + i);
    short4 o;
    o.x = (short)f2bf(v.x); o.y = (short)f2bf(v.y);
    o.z = (short)f2bf(v.z); o.w = (short)f2bf(v.w);
    *(short4*)(out + i) = o;
}

// ------- transpose-cast W_v (1024x1024) ++ W_c (1024x2048) -> WT bf16 [3072][1024] -------
__global__ __launch_bounds__(256) void transpose_w(const float* __restrict__ Wv,
                                                   const float* __restrict__ Wc,
                                                   unsigned short* __restrict__ WT) {
    __shared__ float tile[32][33];
    int n0 = blockIdx.x * 32, k0 = blockIdx.y * 32;
    int t = threadIdx.x;
    int kr = t >> 3, nc = (t & 7) * 4;
    const float* src; int ld; int nn = n0 + nc;
    if (n0 < 1024) { src = Wv; ld = 1024; } else { src = Wc; ld = 2048; nn -= 1024; }
    float4 v = *(const float4*)(src + (size_t)(k0 + kr) * ld + nn);
    tile[kr][nc + 0] = v.x; tile[kr][nc + 1] = v.y;
    tile[kr][nc + 2] = v.z; tile[kr][nc + 3] = v.w;
    __syncthreads();
    int nr = t >> 3, kc = (t & 7) * 4;
    short4 o;
    o.x = (short)f2bf(tile[kc + 0][nr]); o.y = (short)f2bf(tile[kc + 1][nr]);
    o.z = (short)f2bf(tile[kc + 2][nr]); o.w = (short)f2bf(tile[kc + 3][nr]);
    *(short4*)(WT + (size_t)(n0 + nr) * 1024 + k0 + kc) = o;
}

// ---------------- GEMM: C[4096][3072] = A[4096][1024] * BT ----------------
// cols 0..2047 -> kq row-major; cols 2048..3071 -> mv ROW-MAJOR [4096][1024]
// LDS: 128 rows x 32 k (64B rows of four 16B chunks), chunk slot = c ^ ((r>>1)&3)
__global__ __launch_bounds__(256) void gemm_kqv(const unsigned short* __restrict__ A,
                                                const unsigned short* __restrict__ BT,
                                                const float* __restrict__ bv,
                                                const float* __restrict__ bc,
                                                unsigned short* __restrict__ kq,
                                                unsigned short* __restrict__ mv) {
    __shared__ __align__(16) unsigned short As[128 * 32];
    __shared__ __align__(16) unsigned short Bs[128 * 32];
    int m0 = blockIdx.y * 128;
    int n0 = blockIdx.x * 128;
    int tid = threadIdx.x, lane = tid & 63, wv = tid >> 6;
    int wm = wv >> 1, wn = wv & 1;
    int lq = lane & 15, quad = lane >> 4;

    f32x4 zero = {0.f, 0.f, 0.f, 0.f};
    f32x4 acc[4][4];
#pragma unroll
    for (int i = 0; i < 4; ++i)
#pragma unroll
        for (int j = 0; j < 4; ++j) acc[i][j] = zero;

    // staging decode for the two issues per matrix
    int r0 = tid >> 2, s0 = tid & 3;
    int c0 = s0 ^ ((r0 >> 1) & 3);
    int r1 = (tid + 256) >> 2, s1 = tid & 3;
    int c1 = s1 ^ ((r1 >> 1) & 3);

    const unsigned short* Abase0 = A + (size_t)(m0 + r0) * 1024 + c0 * 8;
    const unsigned short* Abase1 = A + (size_t)(m0 + r1) * 1024 + c1 * 8;
    const unsigned short* Bbase0 = BT + (size_t)(n0 + r0) * 1024 + c0 * 8;
    const unsigned short* Bbase1 = BT + (size_t)(n0 + r1) * 1024 + c1 * 8;

    for (int kt = 0; kt < 1024; kt += 32) {
        __syncthreads();  // protect LDS from previous iteration's readers
        g2l16(Abase0 + kt, As + tid * 8);
        g2l16(Abase1 + kt, As + (tid + 256) * 8);
        g2l16(Bbase0 + kt, Bs + tid * 8);
        g2l16(Bbase1 + kt, Bs + (tid + 256) * 8);
        __syncthreads();  // drains vmcnt(0) before barrier release

        short8 af[4], bfr[4];
#pragma unroll
        for (int i = 0; i < 4; ++i) {
            int Ra = wm * 64 + i * 16 + lq;
            af[i] = *(const short8*)(As + Ra * 32 + (quad ^ ((Ra >> 1) & 3)) * 8);
            int Rb = wn * 64 + i * 16 + lq;
            bfr[i] = *(const short8*)(Bs + Rb * 32 + (quad ^ ((Rb >> 1) & 3)) * 8);
        }
#pragma unroll
        for (int mi = 0; mi < 4; ++mi)
#pragma unroll
            for (int ni = 0; ni < 4; ++ni)
                acc[mi][ni] = __builtin_amdgcn_mfma_f32_16x16x32_bf16(af[mi], bfr[ni], acc[mi][ni], 0, 0, 0);
    }

    // epilogue: bias + store (C layout: row = quad*4+reg, col = lq)
#pragma unroll
    for (int mi = 0; mi < 4; ++mi) {
#pragma unroll
        for (int ni = 0; ni < 4; ++ni) {
            int colg = n0 + wn * 64 + ni * 16 + lq;
            float bias = (colg < 1024) ? bv[colg] : bc[colg - 1024];
            if (colg < 2048) {
#pragma unroll
                for (int r = 0; r < 4; ++r) {
                    int rowg = m0 + wm * 64 + mi * 16 + quad * 4 + r;
                    kq[(size_t)rowg * 2048 + colg] = f2bf(acc[mi][ni][r] + bias);
                }
            } else {
                int c = colg - 2048;
#pragma unroll
                for (int r = 0; r < 4; ++r) {
                    int rowg = m0 + wm * 64 + mi * 16 + quad * 4 + r;
                    mv[(size_t)rowg * 1024 + c] = f2bf(acc[mi][ni][r] + bias);
                }
            }
        }
    }
}

// ---------------- transpose mv [4096][1024] -> mvT [b][h][d][j] ----------------
__global__ __launch_bounds__(256) void transpose_mv(const unsigned short* __restrict__ mv,
                                                    unsigned short* __restrict__ mvT) {
    __shared__ __align__(16) unsigned short tile[64 * 72];
    int bh = blockIdx.y, j0 = blockIdx.x * 64;
    int b = bh >> 4, h = bh & 15;
    int t = threadIdx.x;

    int j = t >> 2;
#pragma unroll
    for (int it = 0; it < 2; ++it) {
        int c = (t & 3) + it * 4;
        short8 v = *(const short8*)(mv + (size_t)(b * SS + j0 + j) * 1024 + h * 64 + c * 8);
        *(short8*)(tile + j * 72 + c * 8) = v;
    }
    __syncthreads();

    int d = t >> 2, jc = t & 3;
    unsigned short* dst = mvT + ((size_t)bh * DH + d) * 1024 + j0 + jc * 16;
#pragma unroll
    for (int half = 0; half < 2; ++half) {
        short8 o;
#pragma unroll
        for (int k = 0; k < 8; ++k) o[k] = (short)tile[(jc * 16 + half * 8 + k) * 72 + d];
        *(short8*)(dst + half * 8) = o;
    }
}

// ---------------- fused attention ----------------
__global__ __launch_bounds__(256) void attn_kernel(const unsigned short* __restrict__ kq,
                                                   const unsigned short* __restrict__ mvT,
                                                   const int* __restrict__ mask,
                                                   const float* __restrict__ m_feats,
                                                   float* __restrict__ out0,
                                                   float* __restrict__ out1) {
    __shared__ __align__(16) unsigned short mk_s[16 * 72];
    __shared__ __align__(16) unsigned short s_exp[16 * 1032];
    __shared__ float wsum[4][16];
    __shared__ float inv_s[16];

    int tid = threadIdx.x;
    int lane = tid & 63, wv = tid >> 6;
    int lq = lane & 15, quad = lane >> 4;

    int blk = blockIdx.x;
    int it = blk & 63;
    int bh = blk >> 6;
    int h = bh & (NH - 1), b = bh >> 4;
    int i0 = it * 16;

    if (tid < 128) {
        int row = tid >> 3, ch = tid & 7;
        int4 v = *(const int4*)(kq + (size_t)(b * SS + i0 + row) * 2048 + h * 64 + ch * 8);
        *(int4*)(mk_s + row * 72 + ch * 8) = v;
    }
    __syncthreads();

    short8 a0 = *(const short8*)(mk_s + lq * 72 + 0 * 32 + quad * 8);
    short8 a1 = *(const short8*)(mk_s + lq * 72 + 1 * 32 + quad * 8);

    float sums[4] = {0.f, 0.f, 0.f, 0.f};
    const float SC = 0.18033688011112042f;  // log2(e)/8
    const unsigned short* mqbase = kq + 1024 + h * 64 + quad * 8;
    const int* maskb = mask + b * SS;

    // 1-deep software pipeline over j-tiles
    int jg = wv * 16 + lq;
    size_t ro = (size_t)(b * SS + jg) * 2048;
    short8 nb0 = *(const short8*)(mqbase + ro);
    short8 nb1 = *(const short8*)(mqbase + ro + 32);
    int nmask = maskb[jg];

    for (int jt = wv * 16; jt < SS; jt += 64) {
        short8 b0 = nb0, b1 = nb1;
        int mval = nmask;
        int jcur = jt + lq;

        int jn = (jt + 64 < SS) ? (jt + 64) : (wv * 16);
        int jg2 = jn + lq;
        size_t ro2 = (size_t)(b * SS + jg2) * 2048;
        nb0 = *(const short8*)(mqbase + ro2);
        nb1 = *(const short8*)(mqbase + ro2 + 32);
        nmask = maskb[jg2];

        f32x4 acc = {0.f, 0.f, 0.f, 0.f};
        acc = __builtin_amdgcn_mfma_f32_16x16x32_bf16(a0, b0, acc, 0, 0, 0);
        acc = __builtin_amdgcn_mfma_f32_16x16x32_bf16(a1, b1, acc, 0, 0, 0);
#pragma unroll
        for (int r = 0; r < 4; ++r) {
            float e = mval ? __builtin_amdgcn_exp2f(acc[r] * SC) : 0.f;
            sums[r] += e;
            s_exp[(quad * 4 + r) * 1032 + jcur] = f2bf(e);
        }
    }

#pragma unroll
    for (int r = 0; r < 4; ++r) {
        float s = sums[r];
        s += __shfl_xor(s, 1); s += __shfl_xor(s, 2);
        s += __shfl_xor(s, 4); s += __shfl_xor(s, 8);
        if (lq == 0) wsum[wv][quad * 4 + r] = s;
    }
    __syncthreads();
    if (tid < 16) {
        float s = wsum[0][tid] + wsum[1][tid] + wsum[2][tid] + wsum[3][tid];
        inv_s[tid] = 1.0f / s;
    }
    __syncthreads();

    // PV with 1-deep prefetch of mv fragments
    f32x4 racc = {0.f, 0.f, 0.f, 0.f};
    const unsigned short* mvbase = mvT + ((size_t)bh * DH + wv * 16 + lq) * 1024 + quad * 8;
    short8 nbv = *(const short8*)(mvbase);
#pragma unroll 4
    for (int kt = 0; kt < 32; ++kt) {
        short8 bvf = nbv;
        int kn = (kt < 31) ? (kt + 1) : 31;
        nbv = *(const short8*)(mvbase + kn * 32);
        short8 ae = *(const short8*)(s_exp + lq * 1032 + kt * 32 + quad * 8);
        racc = __builtin_amdgcn_mfma_f32_16x16x32_bf16(ae, bvf, racc, 0, 0, 0);
    }

#pragma unroll
    for (int r = 0; r < 4; ++r) {
        int row = quad * 4 + r;
        size_t o = (size_t)(b * SS + i0 + row) * 1024 + h * 64 + wv * 16 + lq;
        out0[o] = m_feats[o] + racc[r] * inv_s[row];
    }

    size_t wbase = ((size_t)bh * SS + i0) * SS;
#pragma unroll 4
    for (int r = 0; r < 16; ++r) {
        float iv = inv_s[r];
        short4 ev = *(const short4*)(s_exp + r * 1032 + tid * 4);
        float4 wo;
        wo.x = bf2f((unsigned short)ev.x) * iv;
        wo.y = bf2f((unsigned short)ev.y) * iv;
        wo.z = bf2f((unsigned short)ev.z) * iv;
        wo.w = bf2f((unsigned short)ev.w) * iv;
        *(float4*)(out1 + wbase + (size_t)r * SS + tid * 4) = wo;
    }
}

extern "C" void kernel_launch(void* const* d_in, const int* in_sizes, int n_in,
                              void* d_out, int out_size, void* d_ws, size_t ws_size,
                              hipStream_t stream) {
    const float* m_feats = (const float*)d_in[0];
    const int*   mask    = (const int*)d_in[1];
    const float* W_c     = (const float*)d_in[2];
    const float* b_c     = (const float*)d_in[3];
    const float* W_v     = (const float*)d_in[4];
    const float* b_v     = (const float*)d_in[5];

    float* out0 = (float*)d_out;                       // updated_m: 4*1024*1024
    float* out1 = out0 + (size_t)NB * SS * 1024;       // w: 4*16*1024*1024

    unsigned short* mf_bf = (unsigned short*)d_ws;                 // 4096*1024
    unsigned short* WT    = mf_bf + (size_t)4096 * 1024;           // 3072*1024
    unsigned short* kq    = WT + (size_t)3072 * 1024;              // 4096*2048
    unsigned short* mv    = kq + (size_t)4096 * 2048;              // 4096*1024 row-major m_v
    unsigned short* mvT   = mf_bf;                                 // reuse after gemm

    cast_mf<<<dim3(4096), dim3(256), 0, stream>>>(m_feats, mf_bf);
    transpose_w<<<dim3(96, 32), dim3(256), 0, stream>>>(W_v, W_c, WT);
    gemm_kqv<<<dim3(24, 32), dim3(256), 0, stream>>>(mf_bf, WT, b_v, b_c, kq, mv);
    transpose_mv<<<dim3(16, 64), dim3(256), 0, stream>>>(mv, mvT);
    attn_kernel<<<dim3(4096), dim3(256), 0, stream>>>(kq, mvT, mask, m_feats, out0, out1);
}